// Round 1
// baseline (98.789 us; speedup 1.0000x reference)
//
#include <hip/hip_runtime.h>
#include <math.h>

// Label-smoothed cross-entropy loss (XentLoss), MI355X.
// Inputs:
//   d_in[0]: log_probs  float32, (B*T, V) flat = 4096 x 32000
//   d_in[1]: trg        int32,   (B*T,)   = 4096
// Output: d_out[0] = scalar float32 sum over rows.
//
// Memory-bound: 524 MB read -> roofline ~83 us @ 6.3 TB/s.

#define SMOOTHING 0.1

// One block per row. float4-vectorized row sum + per-row loss term.
__global__ __launch_bounds__(256) void xent_row_kernel(
    const float* __restrict__ lp, const int* __restrict__ trg,
    float* __restrict__ row_out, int V) {
  const int row = blockIdx.x;
  const float* rp = lp + (size_t)row * (size_t)V;
  const int tid = threadIdx.x;

  // Vectorized partial sum over the row (V % 4 == 0 for 32000; handle tail anyway).
  float s = 0.0f;
  const int nvec = V >> 2;
  const float4* rp4 = reinterpret_cast<const float4*>(rp);
  for (int i = tid; i < nvec; i += 256) {
    float4 v = rp4[i];
    s += (v.x + v.y) + (v.z + v.w);
  }
  for (int i = (nvec << 2) + tid; i < V; i += 256) s += rp[i];

  // Wave (64-lane) shuffle reduce.
  #pragma unroll
  for (int off = 32; off > 0; off >>= 1) s += __shfl_down(s, off, 64);

  __shared__ float wsum[4];
  const int lane = tid & 63;
  const int wave = tid >> 6;
  if (lane == 0) wsum[wave] = s;
  __syncthreads();

  if (tid == 0) {
    float lp_sum = wsum[0] + wsum[1] + wsum[2] + wsum[3];
    const int t = trg[row];
    const float lp_t = rp[t];
    const float lp_pad = rp[0];

    // Constants in double, matching the reference's Python-double folding.
    const double conf = 1.0 - SMOOTHING;
    const double sm = SMOOTHING / (double)(V - 2);
    const double log_conf = log(conf);
    const double log_sm = log(sm);

    double rv = conf * (log_conf - (double)lp_t)
              + sm * (double)(V - 2) * log_sm
              - sm * ((double)lp_sum - (double)lp_t - (double)lp_pad);
    row_out[row] = (t != 0) ? (float)rv : 0.0f;
  }
}

// Deterministic single-block final sum of the per-row partials.
__global__ __launch_bounds__(256) void xent_final_sum(
    const float* __restrict__ rows, float* __restrict__ out, int n) {
  const int tid = threadIdx.x;
  float s = 0.0f;
  for (int i = tid; i < n; i += 256) s += rows[i];

  #pragma unroll
  for (int off = 32; off > 0; off >>= 1) s += __shfl_down(s, off, 64);

  __shared__ float wsum[4];
  const int lane = tid & 63;
  const int wave = tid >> 6;
  if (lane == 0) wsum[wave] = s;
  __syncthreads();

  if (tid == 0) out[0] = wsum[0] + wsum[1] + wsum[2] + wsum[3];
}

extern "C" void kernel_launch(void* const* d_in, const int* in_sizes, int n_in,
                              void* d_out, int out_size, void* d_ws, size_t ws_size,
                              hipStream_t stream) {
  const float* lp = (const float*)d_in[0];
  const int* trg = (const int*)d_in[1];
  float* out = (float*)d_out;

  const int rows = in_sizes[1];            // B*T = 4096
  const int V = in_sizes[0] / rows;        // 32000

  float* row_out = (float*)d_ws;           // rows * 4 bytes scratch

  xent_row_kernel<<<rows, 256, 0, stream>>>(lp, trg, row_out, V);
  xent_final_sum<<<1, 256, 0, stream>>>(row_out, out, rows);
}